// Round 11
// baseline (36.768 us; speedup 1.0000x reference)
//
#include <hip/hip_runtime.h>
#include <math.h>

// Problem constants (B=2, C=64, H=W=64)
#define BB  2
#define CC  64
#define HH  64
#define WW  64
#define PP  4096
#define CHW 262144
#define KMAX 16
#define NSL 400            // 20x20 union slots for a 4x4 tile
#define SSTR 452           // padded LDS sims stride (floats; covers reads to s=447)

// workspace layout in floats:
#define OFF_XT   0          // 8192*64 fp32
#define OFF_XNH  524288     // bf16 8192*64 (262144 floats)
#define OFF_XNL  786432
#define OFF_DF   1048576    // 8192
#define OFF_PMN  1056768    // 256
#define OFF_PMX  1057024    // 256
#define OFF_W1B  1057280    // bf16 128x64  (4096 floats)
#define OFF_W2B  1061376    // bf16 64x128  (4096 floats)

typedef __bf16 bf16x8 __attribute__((ext_vector_type(8)));
typedef __bf16 bf16x4 __attribute__((ext_vector_type(4)));
typedef float  f32x4  __attribute__((ext_vector_type(4)));

// ---- DPP wave-64 reductions (VALU pipe, no LDS) ----
#define DPP_STEP(v, ctrl, OP) { int _s = __builtin_amdgcn_update_dpp( \
    __float_as_int(v), __float_as_int(v), ctrl, 0xf, 0xf, false); \
    v = OP(v, __int_as_float(_s)); }
__device__ __forceinline__ float addf_(float a, float b) { return a + b; }
__device__ __forceinline__ float wave_max_b(float v) {
    DPP_STEP(v, 0x111, fmaxf) DPP_STEP(v, 0x112, fmaxf) DPP_STEP(v, 0x114, fmaxf)
    DPP_STEP(v, 0x118, fmaxf) DPP_STEP(v, 0x142, fmaxf) DPP_STEP(v, 0x143, fmaxf)
    return __int_as_float(__builtin_amdgcn_readlane(__float_as_int(v), 63));
}
__device__ __forceinline__ float wave_min_b(float v) {
    DPP_STEP(v, 0x111, fminf) DPP_STEP(v, 0x112, fminf) DPP_STEP(v, 0x114, fminf)
    DPP_STEP(v, 0x118, fminf) DPP_STEP(v, 0x142, fminf) DPP_STEP(v, 0x143, fminf)
    return __int_as_float(__builtin_amdgcn_readlane(__float_as_int(v), 63));
}
__device__ __forceinline__ float wave_sum_b(float v) {
    DPP_STEP(v, 0x111, addf_) DPP_STEP(v, 0x112, addf_) DPP_STEP(v, 0x114, addf_)
    DPP_STEP(v, 0x118, addf_) DPP_STEP(v, 0x142, addf_) DPP_STEP(v, 0x143, addf_)
    return __int_as_float(__builtin_amdgcn_readlane(__float_as_int(v), 63));
}

// blocks 0-255: per-32-pixel-row prep (verbatim r10).  blocks 256-257: convert
// w1/w2 fp32 -> bf16 global (elementwise; layouts already row-major as needed).
__global__ __launch_bounds__(256) void k_prep(const float* __restrict__ x,
        float* __restrict__ xt,
        unsigned short* __restrict__ xnh, unsigned short* __restrict__ xnl,
        float* __restrict__ df, float* __restrict__ pmn, float* __restrict__ pmx,
        const float* __restrict__ w1, const float* __restrict__ w2,
        unsigned short* __restrict__ w1b, unsigned short* __restrict__ w2b) {
    if (blockIdx.x >= 256) {
        const float* wsrc = (blockIdx.x == 256) ? w1 : w2;
        unsigned short* wdst = (blockIdx.x == 256) ? w1b : w2b;
        int t = threadIdx.x;
        #pragma unroll
        for (int j = 0; j < 8; ++j) {
            int i4 = t + j*256;                  // 2048 float4 = 8192 floats
            float4 v = *(const float4*)(wsrc + i4*4);
            bf16x4 h; h[0]=(__bf16)v.x; h[1]=(__bf16)v.y; h[2]=(__bf16)v.z; h[3]=(__bf16)v.w;
            *(bf16x4*)&wdst[i4*4] = h;
        }
        return;
    }
    __shared__ float T[64*33];
    __shared__ float xds[2304];               // [c][rr(2)][cc(18)]
    __shared__ float pdf[8*33], pss[8*33];
    __shared__ float sinv[32];
    int t = threadIdx.x;
    int bp0 = blockIdx.x * 32;                // 256 blocks
    int b = bp0 >> 12, p0 = bp0 & 4095;
    int y = p0 >> 6, x0 = p0 & 63;            // x0 in {0,32}
    const float* xb = x + b*CHW + p0;
    #pragma unroll
    for (int i = 0; i < 8; ++i) {
        int idx = t + i*256;
        int c = idx >> 5, pxl = idx & 31;
        T[c*33 + pxl] = xb[c*PP + pxl];
    }
    int m = y >> 1;
    int R0, R1; float ty;
    if ((y & 1) == 0) { R0 = m > 0 ? m-1 : 0; R1 = m; ty = 0.75f; }
    else              { R0 = m; R1 = m < 31 ? m+1 : 31; ty = 0.25f; }
    int h0 = x0 >> 1;
    #pragma unroll
    for (int i = 0; i < 9; ++i) {
        int id = t + i*256;                   // 2304 = 9*256
        int c = id / 36, rem = id - c*36;
        int rr = (rem >= 18) ? 1 : 0, cc = rem - rr*18;
        int row = rr ? R1 : R0;
        int col = h0 - 1 + cc; col = col < 0 ? 0 : (col > 31 ? 31 : col);
        const float* xp = x + b*CHW + c*PP + row*2*WW + col*2;
        xds[id] = (xp[0] + xp[1] + xp[WW] + xp[WW+1]) * 0.25f;
    }
    __syncthreads();
    int px = t & 31, sl = t >> 5;
    int xxp = x0 + px;
    int n2 = xxp >> 1, jx0, jx1; float tx;
    if ((xxp & 1) == 0) { jx0 = n2 > 0 ? n2-1 : 0; jx1 = n2; tx = 0.75f; }
    else                { jx0 = n2; jx1 = n2 < 31 ? n2+1 : 31; tx = 0.25f; }
    int cc0 = jx0 - h0 + 1, cc1 = jx1 - h0 + 1;
    float dfa = 0.f, ss = 0.f;
    #pragma unroll
    for (int ci = 0; ci < 8; ++ci) {
        int c = sl*8 + ci;
        const float* xc = &xds[c*36];
        float a00 = xc[cc0],      a10 = xc[18 + cc0];
        float a01 = xc[cc1],      a11 = xc[18 + cc1];
        float r0 = a00*(1.f-ty) + a10*ty;
        float r1 = a01*(1.f-ty) + a11*ty;
        float xu = r0*(1.f-tx) + r1*tx;
        float v = T[c*33 + px];
        dfa += fabsf(v - xu);
        ss  += v*v;
    }
    pdf[sl*33 + px] = dfa; pss[sl*33 + px] = ss;
    __syncthreads();
    if (t < 32) {
        float d = 0.f, s = 0.f;
        #pragma unroll
        for (int q = 0; q < 8; ++q) { d += pdf[q*33 + t]; s += pss[q*33 + t]; }
        df[bp0 + t] = d;
        sinv[t] = 1.f / fmaxf(sqrtf(s), 1e-12f);
        float mn = d, mx = d;
        #pragma unroll
        for (int off = 1; off < 32; off <<= 1) {
            mn = fminf(mn, __shfl_xor(mn, off));
            mx = fmaxf(mx, __shfl_xor(mx, off));
        }
        if (t == 0) { pmn[blockIdx.x] = mn; pmx[blockIdx.x] = mx; }
    }
    __syncthreads();
    int px2 = t >> 3, cg = t & 7;
    float inv = sinv[px2];
    int bp = bp0 + px2;
    float4 f0, f1; bf16x8 hh, ll;
    #pragma unroll
    for (int k = 0; k < 8; ++k) {
        float v = T[(cg*8 + k)*33 + px2];
        if (k < 4) ((float*)&f0)[k] = v; else ((float*)&f1)[k-4] = v;
        float xnv = v * inv;
        __bf16 hb = (__bf16)xnv;
        float lo = xnv - (float)hb;
        hh[k] = hb; ll[k] = (__bf16)lo;
    }
    *(float4*)&xt[bp*64 + cg*8]     = f0;
    *(float4*)&xt[bp*64 + cg*8 + 4] = f1;
    *(bf16x8*)&xnh[bp*64 + cg*8] = hh;
    *(bf16x8*)&xnl[bp*64 + cg*8] = ll;
}

// fused: per 4x4 tile -- sims MFMA (LDS) -> per-wave top-k/softmax/LN -> FFN MFMA
// 512 blocks x 1024 threads (16 waves; 1 pixel per wave in the top-k phase)
__global__ __launch_bounds__(1024) void k_fuse(
        const unsigned short* __restrict__ xnh,
        const unsigned short* __restrict__ xnl,
        const float* __restrict__ xt, const float* __restrict__ df,
        const float* __restrict__ pmn, const float* __restrict__ pmx,
        const float* __restrict__ gamma, const float* __restrict__ beta,
        const unsigned short* __restrict__ w1b, const float* __restrict__ b1,
        const unsigned short* __restrict__ w2b, const float* __restrict__ b2,
        float* __restrict__ out) {
    __shared__ float  simsL[16*SSTR];   // 28928 B
    __shared__ __bf16 enh16[16*72];     //  2304
    __shared__ __bf16 h1bf[16*136];     //  4352
    __shared__ float  enhT32[16*68];    //  4352
    __shared__ float  smm[2];
    int t = threadIdx.x;
    int bid = blockIdx.x;
    int b = bid >> 8, tid = bid & 255;
    int tyi = tid >> 4, txi = tid & 15;
    int y0 = tyi*4, x0 = txi*4;
    int pbase = (b << 12) + y0*64 + x0;
    int pix0 = pbase & 4095;
    int wv = t >> 6, lane = t & 63;
    int lr = lane & 15, lq = lane >> 4;
    // batch dmin/dmax from per-block partials
    if (t < 64) {
        float v = fminf(pmn[b*128 + t], pmn[b*128 + 64 + t]);
        v = wave_min_b(v);
        if (t == 0) smm[0] = v;
    } else if (t < 128) {
        int u = t & 63;
        float v = fmaxf(pmx[b*128 + u], pmx[b*128 + 64 + u]);
        v = wave_max_b(v);
        if (u == 0) smm[1] = v;
    }
    // ---- phase 1: sims via split-bf16 MFMA (M=16 pixels, 25 n-tiles over waves) ----
    {
        int bpA = pbase + ((lr >> 2) << 6) + (lr & 3);      // A row = tile pixel lr
        const unsigned short* ah = xnh + bpA*64 + lq*8;
        const unsigned short* al = xnl + bpA*64 + lq*8;
        bf16x8 ah0 = *(const bf16x8*)ah, ah1 = *(const bf16x8*)(ah + 32);
        bf16x8 al0 = *(const bf16x8*)al, al1 = *(const bf16x8*)(al + 32);
        for (int nt = wv; nt < 25; nt += 16) {
            int S = nt*16 + lr;
            int rr = S / 20, cc = S - rr*20;
            int ny = y0 + rr - 8, nx = x0 + cc - 8;
            bool vimg = ((unsigned)ny < 64u) && ((unsigned)nx < 64u);
            int bq = vimg ? ((b << 12) + ny*64 + nx) : pbase;
            const unsigned short* bh = xnh + bq*64 + lq*8;
            const unsigned short* bl = xnl + bq*64 + lq*8;
            bf16x8 bh0 = *(const bf16x8*)bh, bh1 = *(const bf16x8*)(bh + 32);
            bf16x8 bl0 = *(const bf16x8*)bl, bl1 = *(const bf16x8*)(bl + 32);
            f32x4 acc = (f32x4){0.f,0.f,0.f,0.f};
            acc = __builtin_amdgcn_mfma_f32_16x16x32_bf16(ah0, bh0, acc, 0, 0, 0);
            acc = __builtin_amdgcn_mfma_f32_16x16x32_bf16(ah0, bl0, acc, 0, 0, 0);
            acc = __builtin_amdgcn_mfma_f32_16x16x32_bf16(al0, bh0, acc, 0, 0, 0);
            acc = __builtin_amdgcn_mfma_f32_16x16x32_bf16(ah1, bh1, acc, 0, 0, 0);
            acc = __builtin_amdgcn_mfma_f32_16x16x32_bf16(ah1, bl1, acc, 0, 0, 0);
            acc = __builtin_amdgcn_mfma_f32_16x16x32_bf16(al1, bh1, acc, 0, 0, 0);
            #pragma unroll
            for (int r = 0; r < 4; ++r) {
                int pxo = lq*4 + r;                         // C row = pixel
                simsL[pxo*SSTR + S] = vimg ? acc[r] : -1e30f;
            }
        }
    }
    __syncthreads();
    // ---- phase 2: wave per pixel: top-k -> softmax agg -> +LN -> enh (LDS) ----
    {
        int i_loc = wv >> 2, j_loc = wv & 3;
        int bp = pbase + i_loc*64 + j_loc;
        const float* srow = &simsL[wv*SSTR];
        float tv[7];
        #pragma unroll
        for (int j = 0; j < 7; ++j) {
            int s = lane + (j << 6);
            bool in = (s < NSL);                            // 400 slots
            int rr = s / 20, cc = s - rr*20;
            int sy = rr - i_loc, sx = cc - j_loc;
            bool ok = in && ((unsigned)sy <= 16u) && ((unsigned)sx <= 16u);
            tv[j] = ok ? srow[s] : -1e30f;
        }
        float lbv = tv[0]; int lbj = 0;
        #pragma unroll
        for (int j = 1; j < 7; ++j) if (tv[j] > lbv) { lbv = tv[j]; lbj = j; }
        float dmin = smm[0], dmax = smm[1];
        float dn = (df[bp] - dmin) / (dmax - dmin + 1e-8f);
        int kk = 1 + (int)rintf(dn * 15.f);
        float S = 0.f, acc = 0.f;
        for (int rnd = 0; rnd < kk; ++rnd) {
            float bv = wave_max_b(lbv);
            unsigned long long msk = __ballot(lbv == bv);
            int src = __ffsll(msk) - 1;
            int js = __builtin_amdgcn_readlane(lbj, src);
            int s = src + (js << 6);
            int rr = s / 20, cc = s - rr*20;
            int q = pbase + (rr - 8)*64 + (cc - 8);
            float e = __expf(bv);
            S += e;
            acc += e * xt[q*64 + lane];
            if (lane == src) {
                #pragma unroll
                for (int j = 0; j < 7; ++j) if (j == js) tv[j] = -3e30f;
            }
            lbv = tv[0]; lbj = 0;
            #pragma unroll
            for (int j = 1; j < 7; ++j) if (tv[j] > lbv) { lbv = tv[j]; lbj = j; }
        }
        float xv = xt[bp*64 + lane];
        float mu = wave_sum_b(xv) * (1.f/64.f);
        float d = xv - mu;
        float var = wave_sum_b(d*d) * (1.f/64.f);
        float xln = d / sqrtf(var + 1e-5f) * gamma[lane] + beta[lane];
        float val = acc / S + xln;
        enhT32[wv*68 + lane] = val;
        enh16[wv*72 + lane] = (__bf16)val;
    }
    __syncthreads();
    // ---- phase 3: FFN GEMM1 (M=16,N=128,K=64), waves 0..7; B from global bf16 ----
    if (wv < 8) {
        int d0 = wv*16;
        f32x4 acc1 = (f32x4){0.f,0.f,0.f,0.f};
        #pragma unroll
        for (int kh = 0; kh < 2; ++kh) {
            int kb = kh*32 + lq*8;
            bf16x8 a  = *(bf16x8*)&enh16[lr*72 + kb];
            bf16x8 bb = *(const bf16x8*)&w1b[(d0 + lr)*64 + kb];
            acc1 = __builtin_amdgcn_mfma_f32_16x16x32_bf16(a, bb, acc1, 0, 0, 0);
        }
        int dd = d0 + lr;
        float bias = b1[dd];
        #pragma unroll
        for (int r = 0; r < 4; ++r) {
            int pxr = lq*4 + r;
            h1bf[pxr*136 + dd] = (__bf16)fmaxf(acc1[r] + bias, 0.f);
        }
    }
    __syncthreads();
    // ---- phase 4: FFN GEMM2 (M=16,N=64,K=128), waves 0..3; out = enh+ffn ----
    if (wv < 4) {
        int c0 = wv*16;
        f32x4 acc2 = (f32x4){0.f,0.f,0.f,0.f};
        #pragma unroll
        for (int kh = 0; kh < 4; ++kh) {
            int kb = kh*32 + lq*8;
            bf16x8 a  = *(bf16x8*)&h1bf[lr*136 + kb];
            bf16x8 bb = *(const bf16x8*)&w2b[(c0 + lr)*128 + kb];
            acc2 = __builtin_amdgcn_mfma_f32_16x16x32_bf16(a, bb, acc2, 0, 0, 0);
        }
        int c = c0 + lr;
        float bias = b2[c];
        #pragma unroll
        for (int r = 0; r < 4; ++r) {
            int pxr = lq*4 + r;
            int pix = pix0 + ((pxr >> 2) << 6) + (pxr & 3);
            out[b*CHW + c*PP + pix] = acc2[r] + bias + enhT32[pxr*68 + c];
        }
    }
}

extern "C" void kernel_launch(void* const* d_in, const int* in_sizes, int n_in,
                              void* d_out, int out_size, void* d_ws, size_t ws_size,
                              hipStream_t stream) {
    const float* x     = (const float*)d_in[0];
    const float* gamma = (const float*)d_in[1];
    const float* beta  = (const float*)d_in[2];
    const float* w1    = (const float*)d_in[3];
    const float* b1    = (const float*)d_in[4];
    const float* w2    = (const float*)d_in[5];
    const float* b2    = (const float*)d_in[6];
    float* ws  = (float*)d_ws;
    float* xt  = ws + OFF_XT;
    float* df  = ws + OFF_DF;
    float* pmn = ws + OFF_PMN;
    float* pmx = ws + OFF_PMX;
    unsigned short* xnh = (unsigned short*)(ws + OFF_XNH);
    unsigned short* xnl = (unsigned short*)(ws + OFF_XNL);
    unsigned short* w1b = (unsigned short*)(ws + OFF_W1B);
    unsigned short* w2b = (unsigned short*)(ws + OFF_W2B);
    float* out = (float*)d_out;

    k_prep<<<258, 256, 0, stream>>>(x, xt, xnh, xnl, df, pmn, pmx, w1, w2, w1b, w2b);
    k_fuse<<<512, 1024, 0, stream>>>(xnh, xnl, xt, df, pmn, pmx, gamma, beta,
                                     w1b, b1, w2b, b2, out);
}

// Round 12
// 35.555 us; speedup vs baseline: 1.0341x; 1.0341x over previous
//
#include <hip/hip_runtime.h>
#include <math.h>

// Problem constants (B=2, C=64, H=W=64)
#define BB  2
#define CC  64
#define HH  64
#define WW  64
#define PP  4096
#define CHW 262144
#define KMAX 16
#define NSL 432            // 18x24 union slots for a 2x8 tile
#define SSTR 436           // padded LDS sims stride (floats)

// workspace layout in floats:
#define OFF_XT   0          // 8192*64 fp32
#define OFF_XNH  524288     // bf16 8192*64 (262144 floats)
#define OFF_XNL  786432
#define OFF_DF   1048576    // 8192
#define OFF_PMN  1056768    // 256
#define OFF_PMX  1057024    // 256

typedef __bf16 bf16x8 __attribute__((ext_vector_type(8)));
typedef __bf16 bf16x4 __attribute__((ext_vector_type(4)));
typedef float  f32x4  __attribute__((ext_vector_type(4)));

// ---- DPP wave-64 reductions (VALU pipe, no LDS) ----
#define DPP_STEP(v, ctrl, OP) { int _s = __builtin_amdgcn_update_dpp( \
    __float_as_int(v), __float_as_int(v), ctrl, 0xf, 0xf, false); \
    v = OP(v, __int_as_float(_s)); }
__device__ __forceinline__ float addf_(float a, float b) { return a + b; }
__device__ __forceinline__ float wave_max_b(float v) {
    DPP_STEP(v, 0x111, fmaxf) DPP_STEP(v, 0x112, fmaxf) DPP_STEP(v, 0x114, fmaxf)
    DPP_STEP(v, 0x118, fmaxf) DPP_STEP(v, 0x142, fmaxf) DPP_STEP(v, 0x143, fmaxf)
    return __int_as_float(__builtin_amdgcn_readlane(__float_as_int(v), 63));
}
__device__ __forceinline__ float wave_min_b(float v) {
    DPP_STEP(v, 0x111, fminf) DPP_STEP(v, 0x112, fminf) DPP_STEP(v, 0x114, fminf)
    DPP_STEP(v, 0x118, fminf) DPP_STEP(v, 0x142, fminf) DPP_STEP(v, 0x143, fminf)
    return __int_as_float(__builtin_amdgcn_readlane(__float_as_int(v), 63));
}
__device__ __forceinline__ float wave_sum_b(float v) {
    DPP_STEP(v, 0x111, addf_) DPP_STEP(v, 0x112, addf_) DPP_STEP(v, 0x114, addf_)
    DPP_STEP(v, 0x118, addf_) DPP_STEP(v, 0x142, addf_) DPP_STEP(v, 0x143, addf_)
    return __int_as_float(__builtin_amdgcn_readlane(__float_as_int(v), 63));
}

// per-32-pixel-row block: inline 2x2 downsample patch, df, transpose -> xt/xnh/xnl,
// per-block min/max -> pmn/pmx (verbatim r10)
__global__ __launch_bounds__(256) void k_prep(const float* __restrict__ x,
        float* __restrict__ xt,
        unsigned short* __restrict__ xnh, unsigned short* __restrict__ xnl,
        float* __restrict__ df, float* __restrict__ pmn, float* __restrict__ pmx) {
    __shared__ float T[64*33];
    __shared__ float xds[2304];               // [c][rr(2)][cc(18)]
    __shared__ float pdf[8*33], pss[8*33];
    __shared__ float sinv[32];
    int t = threadIdx.x;
    int bp0 = blockIdx.x * 32;                // 256 blocks
    int b = bp0 >> 12, p0 = bp0 & 4095;
    int y = p0 >> 6, x0 = p0 & 63;            // x0 in {0,32}
    const float* xb = x + b*CHW + p0;
    #pragma unroll
    for (int i = 0; i < 8; ++i) {
        int idx = t + i*256;
        int c = idx >> 5, pxl = idx & 31;
        T[c*33 + pxl] = xb[c*PP + pxl];
    }
    int m = y >> 1;
    int R0, R1; float ty;
    if ((y & 1) == 0) { R0 = m > 0 ? m-1 : 0; R1 = m; ty = 0.75f; }
    else              { R0 = m; R1 = m < 31 ? m+1 : 31; ty = 0.25f; }
    int h0 = x0 >> 1;
    #pragma unroll
    for (int i = 0; i < 9; ++i) {
        int id = t + i*256;                   // 2304 = 9*256
        int c = id / 36, rem = id - c*36;
        int rr = (rem >= 18) ? 1 : 0, cc = rem - rr*18;
        int row = rr ? R1 : R0;
        int col = h0 - 1 + cc; col = col < 0 ? 0 : (col > 31 ? 31 : col);
        const float* xp = x + b*CHW + c*PP + row*2*WW + col*2;
        xds[id] = (xp[0] + xp[1] + xp[WW] + xp[WW+1]) * 0.25f;
    }
    __syncthreads();
    int px = t & 31, sl = t >> 5;
    int xxp = x0 + px;
    int n2 = xxp >> 1, jx0, jx1; float tx;
    if ((xxp & 1) == 0) { jx0 = n2 > 0 ? n2-1 : 0; jx1 = n2; tx = 0.75f; }
    else                { jx0 = n2; jx1 = n2 < 31 ? n2+1 : 31; tx = 0.25f; }
    int cc0 = jx0 - h0 + 1, cc1 = jx1 - h0 + 1;
    float dfa = 0.f, ss = 0.f;
    #pragma unroll
    for (int ci = 0; ci < 8; ++ci) {
        int c = sl*8 + ci;
        const float* xc = &xds[c*36];
        float a00 = xc[cc0],      a10 = xc[18 + cc0];
        float a01 = xc[cc1],      a11 = xc[18 + cc1];
        float r0 = a00*(1.f-ty) + a10*ty;
        float r1 = a01*(1.f-ty) + a11*ty;
        float xu = r0*(1.f-tx) + r1*tx;
        float v = T[c*33 + px];
        dfa += fabsf(v - xu);
        ss  += v*v;
    }
    pdf[sl*33 + px] = dfa; pss[sl*33 + px] = ss;
    __syncthreads();
    if (t < 32) {
        float d = 0.f, s = 0.f;
        #pragma unroll
        for (int q = 0; q < 8; ++q) { d += pdf[q*33 + t]; s += pss[q*33 + t]; }
        df[bp0 + t] = d;
        sinv[t] = 1.f / fmaxf(sqrtf(s), 1e-12f);
        float mn = d, mx = d;
        #pragma unroll
        for (int off = 1; off < 32; off <<= 1) {
            mn = fminf(mn, __shfl_xor(mn, off));
            mx = fmaxf(mx, __shfl_xor(mx, off));
        }
        if (t == 0) { pmn[blockIdx.x] = mn; pmx[blockIdx.x] = mx; }
    }
    __syncthreads();
    int px2 = t >> 3, cg = t & 7;
    float inv = sinv[px2];
    int bp = bp0 + px2;
    float4 f0, f1; bf16x8 hh, ll;
    #pragma unroll
    for (int k = 0; k < 8; ++k) {
        float v = T[(cg*8 + k)*33 + px2];
        if (k < 4) ((float*)&f0)[k] = v; else ((float*)&f1)[k-4] = v;
        float xnv = v * inv;
        __bf16 hb = (__bf16)xnv;
        float lo = xnv - (float)hb;
        hh[k] = hb; ll[k] = (__bf16)lo;
    }
    *(float4*)&xt[bp*64 + cg*8]     = f0;
    *(float4*)&xt[bp*64 + cg*8 + 4] = f1;
    *(bf16x8*)&xnh[bp*64 + cg*8] = hh;
    *(bf16x8*)&xnl[bp*64 + cg*8] = ll;
}

// fused: per 2x8 tile -- sims MFMA (LDS) -> per-wave top-k/softmax/LN -> FFN MFMA
// 512 blocks x 1024 threads; launch_bounds(1024,8) forces VGPR<=64 -> 2 blocks/CU
__global__ __launch_bounds__(1024, 8) void k_fuse(
        const unsigned short* __restrict__ xnh,
        const unsigned short* __restrict__ xnl,
        const float* __restrict__ xt, const float* __restrict__ df,
        const float* __restrict__ pmn, const float* __restrict__ pmx,
        const float* __restrict__ gamma, const float* __restrict__ beta,
        const float* __restrict__ w1, const float* __restrict__ b1,
        const float* __restrict__ w2, const float* __restrict__ b2,
        float* __restrict__ out) {
    __shared__ float  simsL[16*SSTR];   // 27904 B
    __shared__ __bf16 w1bf[128*72];     // 18432
    __shared__ __bf16 w2bf[64*136];     // 17408
    __shared__ __bf16 enh16[16*72];     //  2304
    __shared__ __bf16 h1bf[16*136];     //  4352
    __shared__ float  enhT32[16*68];    //  4352
    __shared__ float  smm[2];
    int t = threadIdx.x;
    int bid = blockIdx.x;
    int b = bid >> 8, tyi = (bid >> 3) & 31, txi = bid & 7;
    int y0 = tyi*2, x0 = txi*8;
    int pbase = (b << 12) + y0*64 + x0;
    int pix0 = pbase & 4095;
    int wv = t >> 6, lane = t & 63;
    int lr = lane & 15, lq = lane >> 4;
    // stage weights (w1: 128x64 -> [d][c]*72 ; w2: 64x128 -> [c][d]*136)
    #pragma unroll
    for (int j = 0; j < 2; ++j) {
        int i4 = t + j*1024;
        float4 v = *(const float4*)(w1 + i4*4);
        int dd = i4 >> 4, c0 = (i4 & 15)*4;
        bf16x4 h; h[0]=(__bf16)v.x; h[1]=(__bf16)v.y; h[2]=(__bf16)v.z; h[3]=(__bf16)v.w;
        *(bf16x4*)&w1bf[dd*72 + c0] = h;
    }
    #pragma unroll
    for (int j = 0; j < 2; ++j) {
        int i4 = t + j*1024;
        float4 v = *(const float4*)(w2 + i4*4);
        int cc2 = i4 >> 5, d0 = (i4 & 31)*4;
        bf16x4 h; h[0]=(__bf16)v.x; h[1]=(__bf16)v.y; h[2]=(__bf16)v.z; h[3]=(__bf16)v.w;
        *(bf16x4*)&w2bf[cc2*136 + d0] = h;
    }
    // batch dmin/dmax from per-block partials
    if (t < 64) {
        float v = fminf(pmn[b*128 + t], pmn[b*128 + 64 + t]);
        v = wave_min_b(v);
        if (t == 0) smm[0] = v;
    } else if (t < 128) {
        int u = t & 63;
        float v = fmaxf(pmx[b*128 + u], pmx[b*128 + 64 + u]);
        v = wave_max_b(v);
        if (u == 0) smm[1] = v;
    }
    // ---- phase 1: sims via split-bf16 MFMA (M=16 pixels, 27 n-tiles over waves) ----
    {
        int bpA = pbase + ((lr >> 3) << 6) + (lr & 7);      // A row = tile pixel lr
        const unsigned short* ah = xnh + bpA*64 + lq*8;
        const unsigned short* al = xnl + bpA*64 + lq*8;
        bf16x8 ah0 = *(const bf16x8*)ah, ah1 = *(const bf16x8*)(ah + 32);
        bf16x8 al0 = *(const bf16x8*)al, al1 = *(const bf16x8*)(al + 32);
        for (int nt = wv; nt < 27; nt += 16) {
            int S = nt*16 + lr;
            int rr = S / 24, cc = S - rr*24;
            int ny = y0 + rr - 8, nx = x0 + cc - 8;
            bool vimg = ((unsigned)ny < 64u) && ((unsigned)nx < 64u);
            int bq = vimg ? ((b << 12) + ny*64 + nx) : pbase;
            const unsigned short* bh = xnh + bq*64 + lq*8;
            const unsigned short* bl = xnl + bq*64 + lq*8;
            bf16x8 bh0 = *(const bf16x8*)bh, bh1 = *(const bf16x8*)(bh + 32);
            bf16x8 bl0 = *(const bf16x8*)bl, bl1 = *(const bf16x8*)(bl + 32);
            f32x4 acc = (f32x4){0.f,0.f,0.f,0.f};
            acc = __builtin_amdgcn_mfma_f32_16x16x32_bf16(ah0, bh0, acc, 0, 0, 0);
            acc = __builtin_amdgcn_mfma_f32_16x16x32_bf16(ah0, bl0, acc, 0, 0, 0);
            acc = __builtin_amdgcn_mfma_f32_16x16x32_bf16(al0, bh0, acc, 0, 0, 0);
            acc = __builtin_amdgcn_mfma_f32_16x16x32_bf16(ah1, bh1, acc, 0, 0, 0);
            acc = __builtin_amdgcn_mfma_f32_16x16x32_bf16(ah1, bl1, acc, 0, 0, 0);
            acc = __builtin_amdgcn_mfma_f32_16x16x32_bf16(al1, bh1, acc, 0, 0, 0);
            #pragma unroll
            for (int r = 0; r < 4; ++r) {
                int pxo = lq*4 + r;                         // C row = pixel
                simsL[pxo*SSTR + S] = vimg ? acc[r] : -1e30f;
            }
        }
    }
    __syncthreads();
    // ---- phase 2: wave per pixel: top-k -> softmax agg -> +LN -> enh (LDS) ----
    {
        int i_loc = wv >> 3, j_loc = wv & 7;
        int bp = pbase + i_loc*64 + j_loc;
        const float* srow = &simsL[wv*SSTR];
        float tv[7];
        #pragma unroll
        for (int j = 0; j < 7; ++j) {
            int s = lane + (j << 6);
            bool in = (j < 6) || (lane < 48);               // 432 slots
            int rr = s / 24, cc = s - rr*24;
            int sy = rr - i_loc, sx = cc - j_loc;
            bool ok = in && ((unsigned)sy <= 16u) && ((unsigned)sx <= 16u);
            tv[j] = ok ? srow[s] : -1e30f;
        }
        float lbv = tv[0]; int lbj = 0;
        #pragma unroll
        for (int j = 1; j < 7; ++j) if (tv[j] > lbv) { lbv = tv[j]; lbj = j; }
        float dmin = smm[0], dmax = smm[1];
        float dn = (df[bp] - dmin) / (dmax - dmin + 1e-8f);
        int kk = 1 + (int)rintf(dn * 15.f);
        float S = 0.f, acc = 0.f;
        for (int rnd = 0; rnd < kk; ++rnd) {
            float bv = wave_max_b(lbv);
            unsigned long long msk = __ballot(lbv == bv);
            int src = __ffsll(msk) - 1;
            int js = __builtin_amdgcn_readlane(lbj, src);
            int s = src + (js << 6);
            int rr = s / 24, cc = s - rr*24;
            int q = pbase + (rr - 8)*64 + (cc - 8);
            float e = __expf(bv);
            S += e;
            acc += e * xt[q*64 + lane];
            if (lane == src) {
                #pragma unroll
                for (int j = 0; j < 7; ++j) if (j == lbj) tv[j] = -3e30f;
            }
            lbv = tv[0]; lbj = 0;
            #pragma unroll
            for (int j = 1; j < 7; ++j) if (tv[j] > lbv) { lbv = tv[j]; lbj = j; }
        }
        float xv = xt[bp*64 + lane];
        float mu = wave_sum_b(xv) * (1.f/64.f);
        float d = xv - mu;
        float var = wave_sum_b(d*d) * (1.f/64.f);
        float xln = d / sqrtf(var + 1e-5f) * gamma[lane] + beta[lane];
        float val = acc / S + xln;
        enhT32[wv*68 + lane] = val;
        enh16[wv*72 + lane] = (__bf16)val;
    }
    __syncthreads();
    // ---- phase 3: FFN GEMM1 (M=16,N=128,K=64), waves 0..7 ----
    if (wv < 8) {
        int d0 = wv*16;
        f32x4 acc1 = (f32x4){0.f,0.f,0.f,0.f};
        #pragma unroll
        for (int kh = 0; kh < 2; ++kh) {
            int kb = kh*32 + lq*8;
            bf16x8 a  = *(bf16x8*)&enh16[lr*72 + kb];
            bf16x8 bb = *(bf16x8*)&w1bf[(d0 + lr)*72 + kb];
            acc1 = __builtin_amdgcn_mfma_f32_16x16x32_bf16(a, bb, acc1, 0, 0, 0);
        }
        int dd = d0 + lr;
        float bias = b1[dd];
        #pragma unroll
        for (int r = 0; r < 4; ++r) {
            int pxr = lq*4 + r;
            h1bf[pxr*136 + dd] = (__bf16)fmaxf(acc1[r] + bias, 0.f);
        }
    }
    __syncthreads();
    // ---- phase 4: FFN GEMM2 (M=16,N=64,K=128), waves 0..3; out = enh+ffn ----
    if (wv < 4) {
        int c0 = wv*16;
        f32x4 acc2 = (f32x4){0.f,0.f,0.f,0.f};
        #pragma unroll
        for (int kh = 0; kh < 4; ++kh) {
            int kb = kh*32 + lq*8;
            bf16x8 a  = *(bf16x8*)&h1bf[lr*136 + kb];
            bf16x8 bb = *(bf16x8*)&w2bf[(c0 + lr)*136 + kb];
            acc2 = __builtin_amdgcn_mfma_f32_16x16x32_bf16(a, bb, acc2, 0, 0, 0);
        }
        int c = c0 + lr;
        float bias = b2[c];
        #pragma unroll
        for (int r = 0; r < 4; ++r) {
            int pxr = lq*4 + r;
            int pix = pix0 + ((pxr >> 3) << 6) + (pxr & 7);
            out[b*CHW + c*PP + pix] = acc2[r] + bias + enhT32[pxr*68 + c];
        }
    }
}

extern "C" void kernel_launch(void* const* d_in, const int* in_sizes, int n_in,
                              void* d_out, int out_size, void* d_ws, size_t ws_size,
                              hipStream_t stream) {
    const float* x     = (const float*)d_in[0];
    const float* gamma = (const float*)d_in[1];
    const float* beta  = (const float*)d_in[2];
    const float* w1    = (const float*)d_in[3];
    const float* b1    = (const float*)d_in[4];
    const float* w2    = (const float*)d_in[5];
    const float* b2    = (const float*)d_in[6];
    float* ws  = (float*)d_ws;
    float* xt  = ws + OFF_XT;
    float* df  = ws + OFF_DF;
    float* pmn = ws + OFF_PMN;
    float* pmx = ws + OFF_PMX;
    unsigned short* xnh = (unsigned short*)(ws + OFF_XNH);
    unsigned short* xnl = (unsigned short*)(ws + OFF_XNL);
    float* out = (float*)d_out;

    k_prep<<<256, 256, 0, stream>>>(x, xt, xnh, xnl, df, pmn, pmx);
    k_fuse<<<512, 1024, 0, stream>>>(xnh, xnl, xt, df, pmn, pmx, gamma, beta,
                                     w1, b1, w2, b2, out);
}

// Round 13
// 34.562 us; speedup vs baseline: 1.0638x; 1.0287x over previous
//
#include <hip/hip_runtime.h>
#include <math.h>

// Problem constants (B=2, C=64, H=W=64)
#define BB  2
#define CC  64
#define HH  64
#define WW  64
#define PP  4096
#define CHW 262144
#define KMAX 16
#define NSL 432            // 18x24 union slots for a 2x8 tile
#define SSTR 436           // padded LDS sims stride (floats)

// workspace layout in floats:
#define OFF_XT   0          // 8192*64 fp32
#define OFF_XNH  524288     // bf16 8192*64 (262144 floats)
#define OFF_XNL  786432
#define OFF_DF   1048576    // 8192
#define OFF_PMN  1056768    // 256
#define OFF_PMX  1057024    // 256

typedef __bf16 bf16x8 __attribute__((ext_vector_type(8)));
typedef __bf16 bf16x4 __attribute__((ext_vector_type(4)));
typedef float  f32x4  __attribute__((ext_vector_type(4)));

// ---- DPP wave-64 reductions (VALU pipe, no LDS) ----
#define DPP_STEP(v, ctrl, OP) { int _s = __builtin_amdgcn_update_dpp( \
    __float_as_int(v), __float_as_int(v), ctrl, 0xf, 0xf, false); \
    v = OP(v, __int_as_float(_s)); }
__device__ __forceinline__ float addf_(float a, float b) { return a + b; }
__device__ __forceinline__ float wave_max_b(float v) {
    DPP_STEP(v, 0x111, fmaxf) DPP_STEP(v, 0x112, fmaxf) DPP_STEP(v, 0x114, fmaxf)
    DPP_STEP(v, 0x118, fmaxf) DPP_STEP(v, 0x142, fmaxf) DPP_STEP(v, 0x143, fmaxf)
    return __int_as_float(__builtin_amdgcn_readlane(__float_as_int(v), 63));
}
__device__ __forceinline__ float wave_min_b(float v) {
    DPP_STEP(v, 0x111, fminf) DPP_STEP(v, 0x112, fminf) DPP_STEP(v, 0x114, fminf)
    DPP_STEP(v, 0x118, fminf) DPP_STEP(v, 0x142, fminf) DPP_STEP(v, 0x143, fminf)
    return __int_as_float(__builtin_amdgcn_readlane(__float_as_int(v), 63));
}
__device__ __forceinline__ float wave_sum_b(float v) {
    DPP_STEP(v, 0x111, addf_) DPP_STEP(v, 0x112, addf_) DPP_STEP(v, 0x114, addf_)
    DPP_STEP(v, 0x118, addf_) DPP_STEP(v, 0x142, addf_) DPP_STEP(v, 0x143, addf_)
    return __int_as_float(__builtin_amdgcn_readlane(__float_as_int(v), 63));
}

// per-32-pixel-row block: inline 2x2 downsample patch, df, transpose -> xt/xnh/xnl,
// per-block min/max -> pmn/pmx (verbatim r10)
__global__ __launch_bounds__(256) void k_prep(const float* __restrict__ x,
        float* __restrict__ xt,
        unsigned short* __restrict__ xnh, unsigned short* __restrict__ xnl,
        float* __restrict__ df, float* __restrict__ pmn, float* __restrict__ pmx) {
    __shared__ float T[64*33];
    __shared__ float xds[2304];               // [c][rr(2)][cc(18)]
    __shared__ float pdf[8*33], pss[8*33];
    __shared__ float sinv[32];
    int t = threadIdx.x;
    int bp0 = blockIdx.x * 32;                // 256 blocks
    int b = bp0 >> 12, p0 = bp0 & 4095;
    int y = p0 >> 6, x0 = p0 & 63;            // x0 in {0,32}
    const float* xb = x + b*CHW + p0;
    #pragma unroll
    for (int i = 0; i < 8; ++i) {
        int idx = t + i*256;
        int c = idx >> 5, pxl = idx & 31;
        T[c*33 + pxl] = xb[c*PP + pxl];
    }
    int m = y >> 1;
    int R0, R1; float ty;
    if ((y & 1) == 0) { R0 = m > 0 ? m-1 : 0; R1 = m; ty = 0.75f; }
    else              { R0 = m; R1 = m < 31 ? m+1 : 31; ty = 0.25f; }
    int h0 = x0 >> 1;
    #pragma unroll
    for (int i = 0; i < 9; ++i) {
        int id = t + i*256;                   // 2304 = 9*256
        int c = id / 36, rem = id - c*36;
        int rr = (rem >= 18) ? 1 : 0, cc = rem - rr*18;
        int row = rr ? R1 : R0;
        int col = h0 - 1 + cc; col = col < 0 ? 0 : (col > 31 ? 31 : col);
        const float* xp = x + b*CHW + c*PP + row*2*WW + col*2;
        xds[id] = (xp[0] + xp[1] + xp[WW] + xp[WW+1]) * 0.25f;
    }
    __syncthreads();
    int px = t & 31, sl = t >> 5;
    int xxp = x0 + px;
    int n2 = xxp >> 1, jx0, jx1; float tx;
    if ((xxp & 1) == 0) { jx0 = n2 > 0 ? n2-1 : 0; jx1 = n2; tx = 0.75f; }
    else                { jx0 = n2; jx1 = n2 < 31 ? n2+1 : 31; tx = 0.25f; }
    int cc0 = jx0 - h0 + 1, cc1 = jx1 - h0 + 1;
    float dfa = 0.f, ss = 0.f;
    #pragma unroll
    for (int ci = 0; ci < 8; ++ci) {
        int c = sl*8 + ci;
        const float* xc = &xds[c*36];
        float a00 = xc[cc0],      a10 = xc[18 + cc0];
        float a01 = xc[cc1],      a11 = xc[18 + cc1];
        float r0 = a00*(1.f-ty) + a10*ty;
        float r1 = a01*(1.f-ty) + a11*ty;
        float xu = r0*(1.f-tx) + r1*tx;
        float v = T[c*33 + px];
        dfa += fabsf(v - xu);
        ss  += v*v;
    }
    pdf[sl*33 + px] = dfa; pss[sl*33 + px] = ss;
    __syncthreads();
    if (t < 32) {
        float d = 0.f, s = 0.f;
        #pragma unroll
        for (int q = 0; q < 8; ++q) { d += pdf[q*33 + t]; s += pss[q*33 + t]; }
        df[bp0 + t] = d;
        sinv[t] = 1.f / fmaxf(sqrtf(s), 1e-12f);
        float mn = d, mx = d;
        #pragma unroll
        for (int off = 1; off < 32; off <<= 1) {
            mn = fminf(mn, __shfl_xor(mn, off));
            mx = fmaxf(mx, __shfl_xor(mx, off));
        }
        if (t == 0) { pmn[blockIdx.x] = mn; pmx[blockIdx.x] = mx; }
    }
    __syncthreads();
    int px2 = t >> 3, cg = t & 7;
    float inv = sinv[px2];
    int bp = bp0 + px2;
    float4 f0, f1; bf16x8 hh, ll;
    #pragma unroll
    for (int k = 0; k < 8; ++k) {
        float v = T[(cg*8 + k)*33 + px2];
        if (k < 4) ((float*)&f0)[k] = v; else ((float*)&f1)[k-4] = v;
        float xnv = v * inv;
        __bf16 hb = (__bf16)xnv;
        float lo = xnv - (float)hb;
        hh[k] = hb; ll[k] = (__bf16)lo;
    }
    *(float4*)&xt[bp*64 + cg*8]     = f0;
    *(float4*)&xt[bp*64 + cg*8 + 4] = f1;
    *(bf16x8*)&xnh[bp*64 + cg*8] = hh;
    *(bf16x8*)&xnl[bp*64 + cg*8] = ll;
}

// fused: per 2x8 tile -- sims MFMA (LDS) -> per-wave top-k/softmax/LN -> FFN MFMA
// 512 blocks x 1024 threads (16 waves; 1 pixel per wave in the top-k phase)
__global__ __launch_bounds__(1024) void k_fuse(
        const unsigned short* __restrict__ xnh,
        const unsigned short* __restrict__ xnl,
        const float* __restrict__ xt, const float* __restrict__ df,
        const float* __restrict__ pmn, const float* __restrict__ pmx,
        const float* __restrict__ gamma, const float* __restrict__ beta,
        const float* __restrict__ w1, const float* __restrict__ b1,
        const float* __restrict__ w2, const float* __restrict__ b2,
        float* __restrict__ out) {
    __shared__ float  simsL[16*SSTR];   // 27904 B
    __shared__ __bf16 w1bf[128*72];     // 18432
    __shared__ __bf16 w2bf[64*136];     // 17408
    __shared__ __bf16 enh16[16*72];     //  2304
    __shared__ __bf16 h1bf[16*136];     //  4352
    __shared__ float  enhT32[16*68];    //  4352
    __shared__ float  smm[2];
    int t = threadIdx.x;
    int bid = blockIdx.x;
    int b = bid >> 8, tyi = (bid >> 3) & 31, txi = bid & 7;
    int y0 = tyi*2, x0 = txi*8;
    int pbase = (b << 12) + y0*64 + x0;
    int pix0 = pbase & 4095;
    int wv = t >> 6, lane = t & 63;
    int lr = lane & 15, lq = lane >> 4;
    // stage weights (w1: 128x64 -> [d][c]*72 ; w2: 64x128 -> [c][d]*136)
    #pragma unroll
    for (int j = 0; j < 2; ++j) {
        int i4 = t + j*1024;
        float4 v = *(const float4*)(w1 + i4*4);
        int dd = i4 >> 4, c0 = (i4 & 15)*4;
        bf16x4 h; h[0]=(__bf16)v.x; h[1]=(__bf16)v.y; h[2]=(__bf16)v.z; h[3]=(__bf16)v.w;
        *(bf16x4*)&w1bf[dd*72 + c0] = h;
    }
    #pragma unroll
    for (int j = 0; j < 2; ++j) {
        int i4 = t + j*1024;
        float4 v = *(const float4*)(w2 + i4*4);
        int cc2 = i4 >> 5, d0 = (i4 & 31)*4;
        bf16x4 h; h[0]=(__bf16)v.x; h[1]=(__bf16)v.y; h[2]=(__bf16)v.z; h[3]=(__bf16)v.w;
        *(bf16x4*)&w2bf[cc2*136 + d0] = h;
    }
    // batch dmin/dmax from per-block partials
    if (t < 64) {
        float v = fminf(pmn[b*128 + t], pmn[b*128 + 64 + t]);
        v = wave_min_b(v);
        if (t == 0) smm[0] = v;
    } else if (t < 128) {
        int u = t & 63;
        float v = fmaxf(pmx[b*128 + u], pmx[b*128 + 64 + u]);
        v = wave_max_b(v);
        if (u == 0) smm[1] = v;
    }
    // ---- phase 1: sims via split-bf16 MFMA (M=16 pixels, 27 n-tiles over waves) ----
    {
        int bpA = pbase + ((lr >> 3) << 6) + (lr & 7);      // A row = tile pixel lr
        const unsigned short* ah = xnh + bpA*64 + lq*8;
        const unsigned short* al = xnl + bpA*64 + lq*8;
        bf16x8 ah0 = *(const bf16x8*)ah, ah1 = *(const bf16x8*)(ah + 32);
        bf16x8 al0 = *(const bf16x8*)al, al1 = *(const bf16x8*)(al + 32);
        for (int nt = wv; nt < 27; nt += 16) {
            int S = nt*16 + lr;
            int rr = S / 24, cc = S - rr*24;
            int ny = y0 + rr - 8, nx = x0 + cc - 8;
            bool vimg = ((unsigned)ny < 64u) && ((unsigned)nx < 64u);
            int bq = vimg ? ((b << 12) + ny*64 + nx) : pbase;
            const unsigned short* bh = xnh + bq*64 + lq*8;
            const unsigned short* bl = xnl + bq*64 + lq*8;
            bf16x8 bh0 = *(const bf16x8*)bh, bh1 = *(const bf16x8*)(bh + 32);
            bf16x8 bl0 = *(const bf16x8*)bl, bl1 = *(const bf16x8*)(bl + 32);
            f32x4 acc = (f32x4){0.f,0.f,0.f,0.f};
            acc = __builtin_amdgcn_mfma_f32_16x16x32_bf16(ah0, bh0, acc, 0, 0, 0);
            acc = __builtin_amdgcn_mfma_f32_16x16x32_bf16(ah0, bl0, acc, 0, 0, 0);
            acc = __builtin_amdgcn_mfma_f32_16x16x32_bf16(al0, bh0, acc, 0, 0, 0);
            acc = __builtin_amdgcn_mfma_f32_16x16x32_bf16(ah1, bh1, acc, 0, 0, 0);
            acc = __builtin_amdgcn_mfma_f32_16x16x32_bf16(ah1, bl1, acc, 0, 0, 0);
            acc = __builtin_amdgcn_mfma_f32_16x16x32_bf16(al1, bh1, acc, 0, 0, 0);
            #pragma unroll
            for (int r = 0; r < 4; ++r) {
                int pxo = lq*4 + r;                         // C row = pixel
                simsL[pxo*SSTR + S] = vimg ? acc[r] : -1e30f;
            }
        }
    }
    __syncthreads();
    // ---- phase 2: wave per pixel: top-k (pure VALU) -> deferred agg -> +LN ----
    {
        int i_loc = wv >> 3, j_loc = wv & 7;
        int bp = pbase + i_loc*64 + j_loc;
        const float* srow = &simsL[wv*SSTR];
        float tv[7];
        #pragma unroll
        for (int j = 0; j < 7; ++j) {
            int s = lane + (j << 6);
            bool in = (j < 6) || (lane < 48);               // 432 slots
            int rr = s / 24, cc = s - rr*24;
            int sy = rr - i_loc, sx = cc - j_loc;
            bool ok = in && ((unsigned)sy <= 16u) && ((unsigned)sx <= 16u);
            tv[j] = ok ? srow[s] : -1e30f;
        }
        float lbv = tv[0]; int lbj = 0;
        #pragma unroll
        for (int j = 1; j < 7; ++j) if (tv[j] > lbv) { lbv = tv[j]; lbj = j; }
        float dmin = smm[0], dmax = smm[1];
        float dn = (df[bp] - dmin) / (dmax - dmin + 1e-8f);
        int kk = 1 + (int)rintf(dn * 15.f);
        float S = 0.f;
        float esave = 0.f; int qsave = pbase;   // lane r holds round r's (e,q)
        for (int rnd = 0; rnd < kk; ++rnd) {
            float bv = wave_max_b(lbv);
            unsigned long long msk = __ballot(lbv == bv);
            int src = __ffsll(msk) - 1;
            int js = __builtin_amdgcn_readlane(lbj, src);
            int s = src + (js << 6);
            int rr = s / 24, cc = s - rr*24;
            int q = pbase + (rr - 8)*64 + (cc - 8);
            float e = __expf(bv);
            S += e;
            if (lane == rnd) { esave = e; qsave = q; }
            if (lane == src) {
                #pragma unroll
                for (int j = 0; j < 7; ++j) if (j == lbj) tv[j] = -3e30f;
            }
            lbv = tv[0]; lbj = 0;
            #pragma unroll
            for (int j = 1; j < 7; ++j) if (tv[j] > lbv) { lbv = tv[j]; lbj = j; }
        }
        // deferred aggregation: groups of 4 independent xt-row loads (ILP)
        float acc = 0.f;
        #pragma unroll
        for (int g = 0; g < 4; ++g) {
            if (g*4 >= kk) break;
            float e0 = __shfl(esave, g*4+0), e1 = __shfl(esave, g*4+1);
            float e2 = __shfl(esave, g*4+2), e3 = __shfl(esave, g*4+3);
            int   q0 = __shfl(qsave, g*4+0), q1 = __shfl(qsave, g*4+1);
            int   q2 = __shfl(qsave, g*4+2), q3 = __shfl(qsave, g*4+3);
            float v0 = xt[q0*64 + lane], v1 = xt[q1*64 + lane];
            float v2 = xt[q2*64 + lane], v3 = xt[q3*64 + lane];
            acc += e0*v0; acc += e1*v1; acc += e2*v2; acc += e3*v3;
        }
        float xv = xt[bp*64 + lane];
        float mu = wave_sum_b(xv) * (1.f/64.f);
        float d = xv - mu;
        float var = wave_sum_b(d*d) * (1.f/64.f);
        float xln = d / sqrtf(var + 1e-5f) * gamma[lane] + beta[lane];
        float val = acc / S + xln;
        enhT32[wv*68 + lane] = val;
        enh16[wv*72 + lane] = (__bf16)val;
    }
    __syncthreads();
    // ---- phase 3: FFN GEMM1 (M=16,N=128,K=64), waves 0..7 ----
    if (wv < 8) {
        int d0 = wv*16;
        f32x4 acc1 = (f32x4){0.f,0.f,0.f,0.f};
        #pragma unroll
        for (int kh = 0; kh < 2; ++kh) {
            int kb = kh*32 + lq*8;
            bf16x8 a  = *(bf16x8*)&enh16[lr*72 + kb];
            bf16x8 bb = *(bf16x8*)&w1bf[(d0 + lr)*72 + kb];
            acc1 = __builtin_amdgcn_mfma_f32_16x16x32_bf16(a, bb, acc1, 0, 0, 0);
        }
        int dd = d0 + lr;
        float bias = b1[dd];
        #pragma unroll
        for (int r = 0; r < 4; ++r) {
            int pxr = lq*4 + r;
            h1bf[pxr*136 + dd] = (__bf16)fmaxf(acc1[r] + bias, 0.f);
        }
    }
    __syncthreads();
    // ---- phase 4: FFN GEMM2 (M=16,N=64,K=128), waves 0..3; out = enh+ffn ----
    if (wv < 4) {
        int c0 = wv*16;
        f32x4 acc2 = (f32x4){0.f,0.f,0.f,0.f};
        #pragma unroll
        for (int kh = 0; kh < 4; ++kh) {
            int kb = kh*32 + lq*8;
            bf16x8 a  = *(bf16x8*)&h1bf[lr*136 + kb];
            bf16x8 bb = *(bf16x8*)&w2bf[(c0 + lr)*136 + kb];
            acc2 = __builtin_amdgcn_mfma_f32_16x16x32_bf16(a, bb, acc2, 0, 0, 0);
        }
        int c = c0 + lr;
        float bias = b2[c];
        #pragma unroll
        for (int r = 0; r < 4; ++r) {
            int pxr = lq*4 + r;
            int pix = pix0 + ((pxr >> 3) << 6) + (pxr & 7);
            out[b*CHW + c*PP + pix] = acc2[r] + bias + enhT32[pxr*68 + c];
        }
    }
}

extern "C" void kernel_launch(void* const* d_in, const int* in_sizes, int n_in,
                              void* d_out, int out_size, void* d_ws, size_t ws_size,
                              hipStream_t stream) {
    const float* x     = (const float*)d_in[0];
    const float* gamma = (const float*)d_in[1];
    const float* beta  = (const float*)d_in[2];
    const float* w1    = (const float*)d_in[3];
    const float* b1    = (const float*)d_in[4];
    const float* w2    = (const float*)d_in[5];
    const float* b2    = (const float*)d_in[6];
    float* ws  = (float*)d_ws;
    float* xt  = ws + OFF_XT;
    float* df  = ws + OFF_DF;
    float* pmn = ws + OFF_PMN;
    float* pmx = ws + OFF_PMX;
    unsigned short* xnh = (unsigned short*)(ws + OFF_XNH);
    unsigned short* xnl = (unsigned short*)(ws + OFF_XNL);
    float* out = (float*)d_out;

    k_prep<<<256, 256, 0, stream>>>(x, xt, xnh, xnl, df, pmn, pmx);
    k_fuse<<<512, 1024, 0, stream>>>(xnh, xnl, xt, df, pmn, pmx, gamma, beta,
                                     w1, b1, w2, b2, out);
}

// Round 14
// 32.905 us; speedup vs baseline: 1.1174x; 1.0504x over previous
//
#include <hip/hip_runtime.h>
#include <math.h>

// Problem constants (B=2, C=64, H=W=64)
#define BB  2
#define CC  64
#define HH  64
#define WW  64
#define PP  4096
#define CHW 262144
#define KMAX 16
#define NSL 432            // 18x24 union slots for a 2x8 tile
#define SSTR 436           // padded LDS sims stride (floats)

// workspace layout in floats:
#define OFF_XT   0          // 8192*64 fp32
#define OFF_XNH  524288     // bf16 8192*64 (262144 floats)
#define OFF_XNL  786432
#define OFF_DF   1048576    // 8192
#define OFF_PMN  1056768    // 256
#define OFF_PMX  1057024    // 256

typedef __bf16 bf16x8 __attribute__((ext_vector_type(8)));
typedef __bf16 bf16x4 __attribute__((ext_vector_type(4)));
typedef float  f32x4  __attribute__((ext_vector_type(4)));

// ---- DPP wave-64 reductions (VALU pipe, no LDS) ----
#define DPP_STEP(v, ctrl, OP) { int _s = __builtin_amdgcn_update_dpp( \
    __float_as_int(v), __float_as_int(v), ctrl, 0xf, 0xf, false); \
    v = OP(v, __int_as_float(_s)); }
__device__ __forceinline__ float addf_(float a, float b) { return a + b; }
__device__ __forceinline__ float wave_max_b(float v) {
    DPP_STEP(v, 0x111, fmaxf) DPP_STEP(v, 0x112, fmaxf) DPP_STEP(v, 0x114, fmaxf)
    DPP_STEP(v, 0x118, fmaxf) DPP_STEP(v, 0x142, fmaxf) DPP_STEP(v, 0x143, fmaxf)
    return __int_as_float(__builtin_amdgcn_readlane(__float_as_int(v), 63));
}
__device__ __forceinline__ float wave_min_b(float v) {
    DPP_STEP(v, 0x111, fminf) DPP_STEP(v, 0x112, fminf) DPP_STEP(v, 0x114, fminf)
    DPP_STEP(v, 0x118, fminf) DPP_STEP(v, 0x142, fminf) DPP_STEP(v, 0x143, fminf)
    return __int_as_float(__builtin_amdgcn_readlane(__float_as_int(v), 63));
}
__device__ __forceinline__ float wave_sum_b(float v) {
    DPP_STEP(v, 0x111, addf_) DPP_STEP(v, 0x112, addf_) DPP_STEP(v, 0x114, addf_)
    DPP_STEP(v, 0x118, addf_) DPP_STEP(v, 0x142, addf_) DPP_STEP(v, 0x143, addf_)
    return __int_as_float(__builtin_amdgcn_readlane(__float_as_int(v), 63));
}

// per-32-pixel-row block: inline 2x2 downsample patch, df, transpose -> xt/xnh/xnl,
// per-block min/max -> pmn/pmx (r13 + float2 downsample loads)
__global__ __launch_bounds__(256) void k_prep(const float* __restrict__ x,
        float* __restrict__ xt,
        unsigned short* __restrict__ xnh, unsigned short* __restrict__ xnl,
        float* __restrict__ df, float* __restrict__ pmn, float* __restrict__ pmx) {
    __shared__ float T[64*33];
    __shared__ float xds[2304];               // [c][rr(2)][cc(18)]
    __shared__ float pdf[8*33], pss[8*33];
    __shared__ float sinv[32];
    int t = threadIdx.x;
    int bp0 = blockIdx.x * 32;                // 256 blocks
    int b = bp0 >> 12, p0 = bp0 & 4095;
    int y = p0 >> 6, x0 = p0 & 63;            // x0 in {0,32}
    const float* xb = x + b*CHW + p0;
    #pragma unroll
    for (int i = 0; i < 8; ++i) {
        int idx = t + i*256;
        int c = idx >> 5, pxl = idx & 31;
        T[c*33 + pxl] = xb[c*PP + pxl];
    }
    int m = y >> 1;
    int R0, R1; float ty;
    if ((y & 1) == 0) { R0 = m > 0 ? m-1 : 0; R1 = m; ty = 0.75f; }
    else              { R0 = m; R1 = m < 31 ? m+1 : 31; ty = 0.25f; }
    int h0 = x0 >> 1;
    #pragma unroll
    for (int i = 0; i < 9; ++i) {
        int id = t + i*256;                   // 2304 = 9*256
        int c = id / 36, rem = id - c*36;
        int rr = (rem >= 18) ? 1 : 0, cc = rem - rr*18;
        int row = rr ? R1 : R0;
        int col = h0 - 1 + cc; col = col < 0 ? 0 : (col > 31 ? 31 : col);
        const float* xp = x + b*CHW + c*PP + row*2*WW + col*2;
        float2 a0 = *(const float2*)xp;
        float2 a1 = *(const float2*)(xp + WW);
        xds[id] = (a0.x + a0.y + a1.x + a1.y) * 0.25f;
    }
    __syncthreads();
    int px = t & 31, sl = t >> 5;
    int xxp = x0 + px;
    int n2 = xxp >> 1, jx0, jx1; float tx;
    if ((xxp & 1) == 0) { jx0 = n2 > 0 ? n2-1 : 0; jx1 = n2; tx = 0.75f; }
    else                { jx0 = n2; jx1 = n2 < 31 ? n2+1 : 31; tx = 0.25f; }
    int cc0 = jx0 - h0 + 1, cc1 = jx1 - h0 + 1;
    float dfa = 0.f, ss = 0.f;
    #pragma unroll
    for (int ci = 0; ci < 8; ++ci) {
        int c = sl*8 + ci;
        const float* xc = &xds[c*36];
        float a00 = xc[cc0],      a10 = xc[18 + cc0];
        float a01 = xc[cc1],      a11 = xc[18 + cc1];
        float r0 = a00*(1.f-ty) + a10*ty;
        float r1 = a01*(1.f-ty) + a11*ty;
        float xu = r0*(1.f-tx) + r1*tx;
        float v = T[c*33 + px];
        dfa += fabsf(v - xu);
        ss  += v*v;
    }
    pdf[sl*33 + px] = dfa; pss[sl*33 + px] = ss;
    __syncthreads();
    if (t < 32) {
        float d = 0.f, s = 0.f;
        #pragma unroll
        for (int q = 0; q < 8; ++q) { d += pdf[q*33 + t]; s += pss[q*33 + t]; }
        df[bp0 + t] = d;
        sinv[t] = 1.f / fmaxf(sqrtf(s), 1e-12f);
        float mn = d, mx = d;
        #pragma unroll
        for (int off = 1; off < 32; off <<= 1) {
            mn = fminf(mn, __shfl_xor(mn, off));
            mx = fmaxf(mx, __shfl_xor(mx, off));
        }
        if (t == 0) { pmn[blockIdx.x] = mn; pmx[blockIdx.x] = mx; }
    }
    __syncthreads();
    int px2 = t >> 3, cg = t & 7;
    float inv = sinv[px2];
    int bp = bp0 + px2;
    float4 f0, f1; bf16x8 hh, ll;
    #pragma unroll
    for (int k = 0; k < 8; ++k) {
        float v = T[(cg*8 + k)*33 + px2];
        if (k < 4) ((float*)&f0)[k] = v; else ((float*)&f1)[k-4] = v;
        float xnv = v * inv;
        __bf16 hb = (__bf16)xnv;
        float lo = xnv - (float)hb;
        hh[k] = hb; ll[k] = (__bf16)lo;
    }
    *(float4*)&xt[bp*64 + cg*8]     = f0;
    *(float4*)&xt[bp*64 + cg*8 + 4] = f1;
    *(bf16x8*)&xnh[bp*64 + cg*8] = hh;
    *(bf16x8*)&xnl[bp*64 + cg*8] = ll;
}

// fused: per 2x8 tile -- sims MFMA (LDS) -> per-wave top-k/softmax/LN -> FFN MFMA
// 512 blocks x 1024 threads (16 waves; 1 pixel per wave in the top-k phase)
__global__ __launch_bounds__(1024) void k_fuse(
        const unsigned short* __restrict__ xnh,
        const unsigned short* __restrict__ xnl,
        const float* __restrict__ xt, const float* __restrict__ df,
        const float* __restrict__ pmn, const float* __restrict__ pmx,
        const float* __restrict__ gamma, const float* __restrict__ beta,
        const float* __restrict__ w1, const float* __restrict__ b1,
        const float* __restrict__ w2, const float* __restrict__ b2,
        float* __restrict__ out) {
    __shared__ float  simsL[16*SSTR];   // 27904 B
    __shared__ __bf16 w1bf[128*72];     // 18432
    __shared__ __bf16 w2bf[64*136];     // 17408
    __shared__ __bf16 enh16[16*72];     //  2304
    __shared__ __bf16 h1bf[16*136];     //  4352
    __shared__ float  enhT32[16*68];    //  4352
    __shared__ float  smm[2];
    int t = threadIdx.x;
    int bid = blockIdx.x;
    int b = bid >> 8, tyi = (bid >> 3) & 31, txi = bid & 7;
    int y0 = tyi*2, x0 = txi*8;
    int pbase = (b << 12) + y0*64 + x0;
    int pix0 = pbase & 4095;
    int wv = t >> 6, lane = t & 63;
    int lr = lane & 15, lq = lane >> 4;
    // stage weights (w1: 128x64 -> [d][c]*72 ; w2: 64x128 -> [c][d]*136)
    #pragma unroll
    for (int j = 0; j < 2; ++j) {
        int i4 = t + j*1024;
        float4 v = *(const float4*)(w1 + i4*4);
        int dd = i4 >> 4, c0 = (i4 & 15)*4;
        bf16x4 h; h[0]=(__bf16)v.x; h[1]=(__bf16)v.y; h[2]=(__bf16)v.z; h[3]=(__bf16)v.w;
        *(bf16x4*)&w1bf[dd*72 + c0] = h;
    }
    #pragma unroll
    for (int j = 0; j < 2; ++j) {
        int i4 = t + j*1024;
        float4 v = *(const float4*)(w2 + i4*4);
        int cc2 = i4 >> 5, d0 = (i4 & 31)*4;
        bf16x4 h; h[0]=(__bf16)v.x; h[1]=(__bf16)v.y; h[2]=(__bf16)v.z; h[3]=(__bf16)v.w;
        *(bf16x4*)&w2bf[cc2*136 + d0] = h;
    }
    // batch dmin/dmax from per-block partials
    if (t < 64) {
        float v = fminf(pmn[b*128 + t], pmn[b*128 + 64 + t]);
        v = wave_min_b(v);
        if (t == 0) smm[0] = v;
    } else if (t < 128) {
        int u = t & 63;
        float v = fmaxf(pmx[b*128 + u], pmx[b*128 + 64 + u]);
        v = wave_max_b(v);
        if (u == 0) smm[1] = v;
    }
    // ---- phase 1: sims via split-bf16 MFMA (M=16 pixels, 27 n-tiles over waves) ----
    {
        int bpA = pbase + ((lr >> 3) << 6) + (lr & 7);      // A row = tile pixel lr
        const unsigned short* ah = xnh + bpA*64 + lq*8;
        const unsigned short* al = xnl + bpA*64 + lq*8;
        bf16x8 ah0 = *(const bf16x8*)ah, ah1 = *(const bf16x8*)(ah + 32);
        bf16x8 al0 = *(const bf16x8*)al, al1 = *(const bf16x8*)(al + 32);
        for (int nt = wv; nt < 27; nt += 16) {
            int S = nt*16 + lr;
            int rr = S / 24, cc = S - rr*24;
            int ny = y0 + rr - 8, nx = x0 + cc - 8;
            bool vimg = ((unsigned)ny < 64u) && ((unsigned)nx < 64u);
            int bq = vimg ? ((b << 12) + ny*64 + nx) : pbase;
            const unsigned short* bh = xnh + bq*64 + lq*8;
            const unsigned short* bl = xnl + bq*64 + lq*8;
            bf16x8 bh0 = *(const bf16x8*)bh, bh1 = *(const bf16x8*)(bh + 32);
            bf16x8 bl0 = *(const bf16x8*)bl, bl1 = *(const bf16x8*)(bl + 32);
            f32x4 acc = (f32x4){0.f,0.f,0.f,0.f};
            acc = __builtin_amdgcn_mfma_f32_16x16x32_bf16(ah0, bh0, acc, 0, 0, 0);
            acc = __builtin_amdgcn_mfma_f32_16x16x32_bf16(ah0, bl0, acc, 0, 0, 0);
            acc = __builtin_amdgcn_mfma_f32_16x16x32_bf16(al0, bh0, acc, 0, 0, 0);
            acc = __builtin_amdgcn_mfma_f32_16x16x32_bf16(ah1, bh1, acc, 0, 0, 0);
            acc = __builtin_amdgcn_mfma_f32_16x16x32_bf16(ah1, bl1, acc, 0, 0, 0);
            acc = __builtin_amdgcn_mfma_f32_16x16x32_bf16(al1, bh1, acc, 0, 0, 0);
            #pragma unroll
            for (int r = 0; r < 4; ++r) {
                int pxo = lq*4 + r;                         // C row = pixel
                simsL[pxo*SSTR + S] = vimg ? acc[r] : -1e30f;
            }
        }
    }
    __syncthreads();
    // ---- phase 2: wave per pixel: selection-only serial loop; exp/S/decode deferred ----
    {
        int i_loc = wv >> 3, j_loc = wv & 7;
        int bp = pbase + i_loc*64 + j_loc;
        const float* srow = &simsL[wv*SSTR];
        float tv[7];
        #pragma unroll
        for (int j = 0; j < 7; ++j) {
            int s = lane + (j << 6);
            bool in = (j < 6) || (lane < 48);               // 432 slots
            int rr = s / 24, cc = s - rr*24;
            int sy = rr - i_loc, sx = cc - j_loc;
            bool ok = in && ((unsigned)sy <= 16u) && ((unsigned)sx <= 16u);
            tv[j] = ok ? srow[s] : -1e30f;
        }
        float lbv = tv[0]; int lbj = 0;
        #pragma unroll
        for (int j = 1; j < 7; ++j) if (tv[j] > lbv) { lbv = tv[j]; lbj = j; }
        float dmin = smm[0], dmax = smm[1];
        float dn = (df[bp] - dmin) / (dmax - dmin + 1e-8f);
        int kk = 1 + (int)rintf(dn * 15.f);
        // LN inputs hoisted (independent of the selection chain -> ILP)
        float xv = xt[bp*64 + lane];
        float su = wave_sum_b(xv);
        float sq = wave_sum_b(xv*xv);
        float mu = su * (1.f/64.f);
        float var = sq * (1.f/64.f) - mu*mu;
        // selection loop: pure VALU; lane rnd saves (bv, s)
        float bvsave = 0.f; int ssave = 200;    // slot (8,8) -> q = pbase (safe pad)
        for (int rnd = 0; rnd < kk; ++rnd) {
            float bv = wave_max_b(lbv);
            unsigned long long msk = __ballot(lbv == bv);
            int src = __ffsll(msk) - 1;
            int js = __builtin_amdgcn_readlane(lbj, src);
            int s = src + (js << 6);
            if (lane == rnd) { bvsave = bv; ssave = s; }
            if (lane == src) {
                #pragma unroll
                for (int j = 0; j < 7; ++j) if (j == lbj) tv[j] = -3e30f;
            }
            lbv = tv[0]; lbj = 0;
            #pragma unroll
            for (int j = 1; j < 7; ++j) if (tv[j] > lbv) { lbv = tv[j]; lbj = j; }
        }
        // parallel epilogue: exp, S, slot decode all at once
        float ee = (lane < kk) ? __expf(bvsave) : 0.f;
        float S = wave_sum_b(ee);
        int rr2 = ssave / 24, cc2 = ssave - rr2*24;
        int qq = pbase + (rr2 - 8)*64 + (cc2 - 8);
        float acc = 0.f;
        #pragma unroll
        for (int g = 0; g < 4; ++g) {
            if (g*4 >= kk) break;
            float e0 = __shfl(ee, g*4+0), e1 = __shfl(ee, g*4+1);
            float e2 = __shfl(ee, g*4+2), e3 = __shfl(ee, g*4+3);
            int   q0 = __shfl(qq, g*4+0), q1 = __shfl(qq, g*4+1);
            int   q2 = __shfl(qq, g*4+2), q3 = __shfl(qq, g*4+3);
            float v0 = xt[q0*64 + lane], v1 = xt[q1*64 + lane];
            float v2 = xt[q2*64 + lane], v3 = xt[q3*64 + lane];
            acc += e0*v0; acc += e1*v1; acc += e2*v2; acc += e3*v3;
        }
        float xln = (xv - mu) / sqrtf(var + 1e-5f) * gamma[lane] + beta[lane];
        float val = acc / S + xln;
        enhT32[wv*68 + lane] = val;
        enh16[wv*72 + lane] = (__bf16)val;
    }
    __syncthreads();
    // ---- phase 3: FFN GEMM1 (M=16,N=128,K=64), waves 0..7 ----
    if (wv < 8) {
        int d0 = wv*16;
        f32x4 acc1 = (f32x4){0.f,0.f,0.f,0.f};
        #pragma unroll
        for (int kh = 0; kh < 2; ++kh) {
            int kb = kh*32 + lq*8;
            bf16x8 a  = *(bf16x8*)&enh16[lr*72 + kb];
            bf16x8 bb = *(bf16x8*)&w1bf[(d0 + lr)*72 + kb];
            acc1 = __builtin_amdgcn_mfma_f32_16x16x32_bf16(a, bb, acc1, 0, 0, 0);
        }
        int dd = d0 + lr;
        float bias = b1[dd];
        #pragma unroll
        for (int r = 0; r < 4; ++r) {
            int pxr = lq*4 + r;
            h1bf[pxr*136 + dd] = (__bf16)fmaxf(acc1[r] + bias, 0.f);
        }
    }
    __syncthreads();
    // ---- phase 4: FFN GEMM2 (M=16,N=64,K=128), waves 0..3; out = enh+ffn ----
    if (wv < 4) {
        int c0 = wv*16;
        f32x4 acc2 = (f32x4){0.f,0.f,0.f,0.f};
        #pragma unroll
        for (int kh = 0; kh < 4; ++kh) {
            int kb = kh*32 + lq*8;
            bf16x8 a  = *(bf16x8*)&h1bf[lr*136 + kb];
            bf16x8 bb = *(bf16x8*)&w2bf[(c0 + lr)*136 + kb];
            acc2 = __builtin_amdgcn_mfma_f32_16x16x32_bf16(a, bb, acc2, 0, 0, 0);
        }
        int c = c0 + lr;
        float bias = b2[c];
        #pragma unroll
        for (int r = 0; r < 4; ++r) {
            int pxr = lq*4 + r;
            int pix = pix0 + ((pxr >> 3) << 6) + (pxr & 7);
            out[b*CHW + c*PP + pix] = acc2[r] + bias + enhT32[pxr*68 + c];
        }
    }
}

extern "C" void kernel_launch(void* const* d_in, const int* in_sizes, int n_in,
                              void* d_out, int out_size, void* d_ws, size_t ws_size,
                              hipStream_t stream) {
    const float* x     = (const float*)d_in[0];
    const float* gamma = (const float*)d_in[1];
    const float* beta  = (const float*)d_in[2];
    const float* w1    = (const float*)d_in[3];
    const float* b1    = (const float*)d_in[4];
    const float* w2    = (const float*)d_in[5];
    const float* b2    = (const float*)d_in[6];
    float* ws  = (float*)d_ws;
    float* xt  = ws + OFF_XT;
    float* df  = ws + OFF_DF;
    float* pmn = ws + OFF_PMN;
    float* pmx = ws + OFF_PMX;
    unsigned short* xnh = (unsigned short*)(ws + OFF_XNH);
    unsigned short* xnl = (unsigned short*)(ws + OFF_XNL);
    float* out = (float*)d_out;

    k_prep<<<256, 256, 0, stream>>>(x, xt, xnh, xnl, df, pmn, pmx);
    k_fuse<<<512, 1024, 0, stream>>>(xnh, xnl, xt, df, pmn, pmx, gamma, beta,
                                     w1, b1, w2, b2, out);
}